// Round 3
// baseline (1114.460 us; speedup 1.0000x reference)
//
#include <hip/hip_runtime.h>
#include <hip/hip_cooperative_groups.h>
#include <hip/hip_bf16.h>

namespace cg = cooperative_groups;

#define ALPHA 0.2f
// N=1024 particles, F_IN=6, NH=64, H=4 heads, T=12 steps.

typedef short bf16x8 __attribute__((ext_vector_type(8)));   // 8 bf16 (4 VGPRs)
typedef float f32x4 __attribute__((ext_vector_type(4)));

__device__ __forceinline__ float wsum(float v){
  #pragma unroll
  for (int m = 1; m < 64; m <<= 1) v += __shfl_xor(v, m, 64);
  return v;
}
__device__ __forceinline__ float wmax(float v){
  #pragma unroll
  for (int m = 1; m < 64; m <<= 1) v = fmaxf(v, __shfl_xor(v, m, 64));
  return v;
}

// Dtype detector: bf16 data never contains inf/NaN bit patterns (inputs finite);
// f32 data viewed as ushorts has ~0.78% such patterns. flag=1 -> f32; 0 -> bf16.
__global__ void k_detect(const unsigned short* __restrict__ s, int n, int* __restrict__ flag){
  int i = blockIdx.x * 256 + threadIdx.x;
  if (i < n){
    unsigned short u = s[i];
    if ((u & 0x7F80u) == 0x7F80u) atomicOr(flag, 1);
  }
}

// Merged conversion: states (73728 -> xs) + all 12 weight arrays (-> padded wsW).
struct Ptr13 { const void* p[13]; };
__global__ void k_cvtAll(Ptr13 src, float* __restrict__ xs, float* __restrict__ wsW,
                         const int* __restrict__ flag){
  const int n = blockIdx.x * 256 + threadIdx.x;
  const int F = *flag;
  if (n < 73728){
    xs[n] = F ? ((const float*)src.p[0])[n]
              : __bfloat162float(((const __hip_bfloat16*)src.p[0])[n]);
    return;
  }
  const int m = n - 73728;
  if (m >= 10788) return;
  const int segend[12] = {1536,2048,3584,3596,5132,5644,7180,7192,8728,9240,10776,10788};
  const int dstoff[12] = {0,1536,2048,3584,3600,5136,5648,7184,7200,8736,9248,10784};
  int seg = 0;
  #pragma unroll
  for (int i = 0; i < 12; ++i) if (m >= segend[i]) seg = i + 1;
  const int local = m - (seg ? segend[seg - 1] : 0);
  float v;
  if (F) v = ((const float*)src.p[seg + 1])[local];
  else   v = __bfloat162float(((const __hip_bfloat16*)src.p[seg + 1])[local]);
  wsW[dstoff[seg] + local] = v;
}

// Batched prep for MFMA attend: hW row computed in fp32, emitted as bf16
// V-TRANSPOSED Vt[(b*4+h)*64 + k][j] (row stride 1032 bf16) via LDS transpose.
// Also fsd fp32. Block: 1 head (z), 256 rows (x), instance (y).
__launch_bounds__(256)
__global__ void k_prepT(const float* __restrict__ X, const float* __restrict__ W,
                        const float* __restrict__ a,
                        __hip_bfloat16* __restrict__ Vt, float* __restrict__ fsd)
{
  __shared__ float WS[384];    // W[h]: [6][64]
  __shared__ float aS[128];
  __shared__ __align__(16) __hip_bfloat16 tileT[64 * 264];  // [k][row], pad 8
  const int t = threadIdx.x;
  const int b = blockIdx.y;
  const int h = blockIdx.z;
  const int row0 = blockIdx.x * 256;
  const int row = row0 + t;
  for (int i = t; i < 384; i += 256) WS[i] = W[h * 384 + i];
  if (t < 128) aS[t] = a[h * 128 + t];
  __syncthreads();
  float x[6];
  const float* xp = X + ((size_t)b * 1024 + row) * 6;
  #pragma unroll
  for (int f = 0; f < 6; ++f) x[f] = xp[f];
  float fs = 0.f, fd = 0.f;
  for (int k = 0; k < 64; ++k){
    float v = 0.f;
    #pragma unroll
    for (int f = 0; f < 6; ++f) v += x[f] * WS[f * 64 + k];
    fs += v * aS[k]; fd += v * aS[64 + k];
    tileT[k * 264 + t] = __float2bfloat16(v);
  }
  fsd[(((size_t)b * 4 + h) * 2 + 0) * 1024 + row] = fs;
  fsd[(((size_t)b * 4 + h) * 2 + 1) * 1024 + row] = fd;
  __syncthreads();
  const int k = t >> 2, seg = t & 3;
  __hip_bfloat16* dst = Vt + (((size_t)b * 4 + h) * 64 + k) * 1032 + row0 + seg * 64;
  const __hip_bfloat16* src = tileT + k * 264 + seg * 64;
  #pragma unroll
  for (int i = 0; i < 8; ++i)
    ((uint4*)dst)[i] = ((const uint4*)src)[i];
}

// MFMA head-attend v3: block = 1 head x 64 rows (4 waves x 16 rows), 64 feats.
// Softmax weights (A-fragments) fully in-register (row=lane&15, k=(lane>>4)*8+i).
// B-fragments read DIRECTLY from global Vt (L2-resident): no in-loop barriers.
__launch_bounds__(256)
__global__ void k_attM(const __hip_bfloat16* __restrict__ Vt, const float* __restrict__ fsd,
                       const float* __restrict__ Wout, const float* __restrict__ aout,
                       float* __restrict__ hW2part, float* __restrict__ f2part)
{
  const int h = blockIdx.x & 3;
  const int row0 = (blockIdx.x >> 2) * 64;
  const int b = blockIdx.y;
  const int t = threadIdx.x;
  const int wv = t >> 6, lane = t & 63;
  const int n = lane & 15, q = lane >> 4;
  const size_t bh = (size_t)b * 4 + h;

  __shared__ float dS[1024];
  __shared__ float WoS[384];
  __shared__ float aoS[12];
  __shared__ float redW[4];

  const float* fb = fsd + bh * 2048;
  float4 dv = *(const float4*)(fb + 1024 + t * 4);
  for (int i = t; i < 384; i += 256) WoS[i] = Wout[h * 384 + i];
  if (t < 12) aoS[t] = aout[t];
  *(float4*)&dS[t * 4] = dv;
  const float sW = fb[row0 + wv * 16 + n];        // this lane's attention-row score
  float lm = fmaxf(fmaxf(dv.x, dv.y), fmaxf(dv.z, dv.w));
  lm = wmax(lm);
  if (lane == 0) redW[wv] = lm;
  __syncthreads();
  const float maxd = fmaxf(fmaxf(redW[0], redW[1]), fmaxf(redW[2], redW[3]));
  float mW = sW + maxd; mW = fmaxf(mW, ALPHA * mW);   // leaky(sW+maxd) = row max of e

  const __hip_bfloat16* vbase = Vt + (bh * 64 + n) * 1032 + q * 8;
  f32x4 acc[4];
  #pragma unroll
  for (int nt = 0; nt < 4; ++nt) acc[nt] = (f32x4){0.f, 0.f, 0.f, 0.f};
  float den = 0.f;

  for (int jt = 0; jt < 16; ++jt){
    bf16x8 b0[4], b1[4];
    #pragma unroll
    for (int nt = 0; nt < 4; ++nt){
      b0[nt] = *(const bf16x8*)(vbase + nt * 16512 + jt * 64);
      b1[nt] = *(const bf16x8*)(vbase + nt * 16512 + jt * 64 + 32);
    }
    // A-fragments for this lane: rows n, j = jt*64 + {0,32} + q*8 + i
    const float* dp = &dS[jt * 64 + q * 8];
    float d0[8], d1[8];
    *(float4*)&d0[0] = *(const float4*)(dp);
    *(float4*)&d0[4] = *(const float4*)(dp + 4);
    *(float4*)&d1[0] = *(const float4*)(dp + 32);
    *(float4*)&d1[4] = *(const float4*)(dp + 36);
    bf16x8 a0, a1;
    #pragma unroll
    for (int i = 0; i < 8; ++i){
      float e0 = sW + d0[i]; e0 = fmaxf(e0, ALPHA * e0);
      __hip_bfloat16 w0 = __float2bfloat16(__expf(fminf(e0 - mW, 0.f)));
      a0[i] = __builtin_bit_cast(short, w0);
      den += __bfloat162float(w0);                  // den consistent with bf16 A
      float e1 = sW + d1[i]; e1 = fmaxf(e1, ALPHA * e1);
      __hip_bfloat16 w1 = __float2bfloat16(__expf(fminf(e1 - mW, 0.f)));
      a1[i] = __builtin_bit_cast(short, w1);
      den += __bfloat162float(w1);
    }
    #pragma unroll
    for (int nt = 0; nt < 4; ++nt)
      acc[nt] = __builtin_amdgcn_mfma_f32_16x16x32_bf16(a0, b0[nt], acc[nt], 0, 0, 0);
    #pragma unroll
    for (int nt = 0; nt < 4; ++nt)
      acc[nt] = __builtin_amdgcn_mfma_f32_16x16x32_bf16(a1, b1[nt], acc[nt], 0, 0, 0);
  }
  // full den per row n: reduce over the 4 q-lanes sharing row n
  den += __shfl_xor(den, 16, 64);
  den += __shfl_xor(den, 32, 64);

  // epilogue: D[row=q*4+reg][feat=nt*16+n]; /den, ELU, project to 6 feats.
  float o[4][6];
  #pragma unroll
  for (int reg = 0; reg < 4; ++reg)
    #pragma unroll
    for (int f = 0; f < 6; ++f) o[reg][f] = 0.f;
  #pragma unroll
  for (int reg = 0; reg < 4; ++reg){
    const float dn = __shfl(den, q * 4 + reg, 64);  // den of row q*4+reg (>= 1)
    #pragma unroll
    for (int nt = 0; nt < 4; ++nt){
      float v = acc[nt][reg] / dn;
      v = v > 0.f ? v : (__expf(v) - 1.f);          // ELU
      #pragma unroll
      for (int f = 0; f < 6; ++f) o[reg][f] += v * WoS[(nt * 16 + n) * 6 + f];
    }
  }
  #pragma unroll
  for (int mm = 1; mm < 16; mm <<= 1)
    #pragma unroll
    for (int reg = 0; reg < 4; ++reg)
      #pragma unroll
      for (int f = 0; f < 6; ++f) o[reg][f] += __shfl_xor(o[reg][f], mm, 64);
  if (n == 0){
    #pragma unroll
    for (int reg = 0; reg < 4; ++reg){
      const int row = row0 + wv * 16 + q * 4 + reg;
      float* hp = hW2part + bh * 6144 + row * 6;
      float fs = 0.f, fd = 0.f;
      #pragma unroll
      for (int f = 0; f < 6; ++f){
        hp[f] = o[reg][f];
        fs += o[reg][f] * aoS[f]; fd += o[reg][f] * aoS[6 + f];
      }
      f2part[bh * 2048 + row]        = fs;
      f2part[bh * 2048 + 1024 + row] = fd;
    }
  }
}

// Phase 2 fused: ALL 12 recurrence steps in ONE cooperative kernel.
// 256 blocks x 256 threads = 1 block/CU (co-resident). Per step:
//   role A (attP): head-attend, block=(h=bid&3, 16 rows), 4 waves split j,
//                  in-register softmax A-frags, B-frags direct from L2 VtP.
//   grid.sync()
//   role B (attB): sum partials, output attend (K=6), h_t = Lx + out,
//                  write next VtP (transposed bf16) + fh. block = 4 rows.
//   grid.sync()  (elided after last step)
// Replaces 24 kernel launches + 2 memsets with 1 launch + 23 grid syncs.
__launch_bounds__(256)
__global__ void k_phase2(const float* __restrict__ Lx, float* __restrict__ h_all,
                         const float* __restrict__ Who, const float* __restrict__ aho,
                         const float* __restrict__ Wh, const float* __restrict__ ah,
                         __hip_bfloat16* __restrict__ VtP, float* __restrict__ fh,
                         float* __restrict__ hW2part, float* __restrict__ f2part)
{
  cg::grid_group gg = cg::this_grid();
  const int bid = blockIdx.x;
  const int t = threadIdx.x;
  const int wv = t >> 6, lane = t & 63;
  const int n = lane & 15, q = lane >> 4;
  const int hP = bid & 3;                 // role-A head
  const int row0P = (bid >> 2) * 16;      // role-A row block
  const int row0B = bid * 4;              // role-B row block

  __shared__ float WoS[384];              // Who slice for hP
  __shared__ float aoS[12];
  __shared__ float WnS[1536];             // Wh (full)
  __shared__ float anS[512];              // ah (full)
  __shared__ float dS[1024];              // role-A dest scores
  __shared__ float redW[4];
  __shared__ float accS[4][16][65];       // role-A cross-wave acc (+1 pad)
  __shared__ float denP[4][16];
  __shared__ float featS[6144];           // role-B summed features
  __shared__ float dSb[1024];
  __shared__ float sSb[4];
  __shared__ float htS[4][6];

  // persistent weights (loaded once for all 12 steps)
  for (int i = t; i < 384; i += 256) WoS[i] = Who[hP * 384 + i];
  if (t < 12) aoS[t] = aho[t];
  for (int i = t; i < 1536; i += 256) WnS[i] = Wh[i];
  for (int i = t; i < 512;  i += 256) anS[i] = ah[i];

  // zero initial recurrent state (replaces 2 memset dispatches)
  {
    unsigned int* vz = (unsigned int*)VtP;          // 4*64*1024 bf16 = 131072 u32
    const int gid = bid * 256 + t;
    for (int i = gid; i < 131072; i += 65536) vz[i] = 0u;
    for (int i = gid; i < 8192; i += 65536) fh[i] = 0.f;
  }
  gg.sync();

  for (int step = 0; step < 12; ++step){
    // ================= role A: head attend (MFMA) =================
    {
      const float* fb = fh + (size_t)hP * 2048;
      float4 dv = *(const float4*)(fb + 1024 + t * 4);
      *(float4*)&dS[t * 4] = dv;
      const float sW = fb[row0P + n];
      float lm = fmaxf(fmaxf(dv.x, dv.y), fmaxf(dv.z, dv.w));
      lm = wmax(lm);
      if (lane == 0) redW[wv] = lm;
      __syncthreads();
      const float maxd = fmaxf(fmaxf(redW[0], redW[1]), fmaxf(redW[2], redW[3]));
      float mW = sW + maxd; mW = fmaxf(mW, ALPHA * mW);

      const __hip_bfloat16* vbase = VtP + ((size_t)hP * 64 + n) * 1024 + q * 8;
      f32x4 acc[4];
      #pragma unroll
      for (int nt = 0; nt < 4; ++nt) acc[nt] = (f32x4){0.f, 0.f, 0.f, 0.f};
      float den = 0.f;

      #pragma unroll
      for (int u = 0; u < 4; ++u){
        const int jt = wv * 4 + u;
        bf16x8 b0[4], b1[4];
        #pragma unroll
        for (int nt = 0; nt < 4; ++nt){
          b0[nt] = *(const bf16x8*)(vbase + nt * 16384 + jt * 64);
          b1[nt] = *(const bf16x8*)(vbase + nt * 16384 + jt * 64 + 32);
        }
        const float* dp = &dS[jt * 64 + q * 8];
        float d0[8], d1[8];
        *(float4*)&d0[0] = *(const float4*)(dp);
        *(float4*)&d0[4] = *(const float4*)(dp + 4);
        *(float4*)&d1[0] = *(const float4*)(dp + 32);
        *(float4*)&d1[4] = *(const float4*)(dp + 36);
        bf16x8 a0, a1;
        #pragma unroll
        for (int i = 0; i < 8; ++i){
          float e0 = sW + d0[i]; e0 = fmaxf(e0, ALPHA * e0);
          __hip_bfloat16 w0 = __float2bfloat16(__expf(fminf(e0 - mW, 0.f)));
          a0[i] = __builtin_bit_cast(short, w0);
          den += __bfloat162float(w0);
          float e1 = sW + d1[i]; e1 = fmaxf(e1, ALPHA * e1);
          __hip_bfloat16 w1 = __float2bfloat16(__expf(fminf(e1 - mW, 0.f)));
          a1[i] = __builtin_bit_cast(short, w1);
          den += __bfloat162float(w1);
        }
        #pragma unroll
        for (int nt = 0; nt < 4; ++nt)
          acc[nt] = __builtin_amdgcn_mfma_f32_16x16x32_bf16(a0, b0[nt], acc[nt], 0, 0, 0);
        #pragma unroll
        for (int nt = 0; nt < 4; ++nt)
          acc[nt] = __builtin_amdgcn_mfma_f32_16x16x32_bf16(a1, b1[nt], acc[nt], 0, 0, 0);
      }
      den += __shfl_xor(den, 16, 64);
      den += __shfl_xor(den, 32, 64);
      if (lane < 16) denP[wv][lane] = den;
      #pragma unroll
      for (int nt = 0; nt < 4; ++nt)
        #pragma unroll
        for (int reg = 0; reg < 4; ++reg)
          accS[wv][q * 4 + reg][nt * 16 + n] = acc[nt][reg];
      __syncthreads();

      const int r = t >> 4, kq = t & 15;
      const float dn = denP[0][r] + denP[1][r] + denP[2][r] + denP[3][r];  // >= 1
      float o[6] = {0.f,0.f,0.f,0.f,0.f,0.f};
      #pragma unroll
      for (int j4 = 0; j4 < 4; ++j4){
        const int k = kq * 4 + j4;
        float v = (accS[0][r][k] + accS[1][r][k] + accS[2][r][k] + accS[3][r][k]) / dn;
        v = v > 0.f ? v : (__expf(v) - 1.f);        // ELU
        #pragma unroll
        for (int f = 0; f < 6; ++f) o[f] += v * WoS[k * 6 + f];
      }
      #pragma unroll
      for (int mm = 1; mm < 16; mm <<= 1)
        #pragma unroll
        for (int f = 0; f < 6; ++f) o[f] += __shfl_xor(o[f], mm, 64);
      if (kq == 0){
        const int row = row0P + r;
        float* hp = hW2part + (size_t)hP * 6144 + row * 6;
        float fs = 0.f, fd = 0.f;
        #pragma unroll
        for (int f = 0; f < 6; ++f){
          hp[f] = o[f];
          fs += o[f] * aoS[f]; fd += o[f] * aoS[6 + f];
        }
        f2part[(size_t)hP * 2048 + row]        = fs;
        f2part[(size_t)hP * 2048 + 1024 + row] = fd;
      }
    }
    gg.sync();

    // ================= role B: combine + advance =================
    {
      for (int i = t; i < 6144; i += 256)
        featS[i] = hW2part[i] + hW2part[6144 + i] + hW2part[12288 + i] + hW2part[18432 + i];
      for (int i = t; i < 1024; i += 256)
        dSb[i] = f2part[1024 + i] + f2part[3072 + i] + f2part[5120 + i] + f2part[7168 + i];
      if (t < 4){
        const int r = row0B + t;
        sSb[t] = f2part[r] + f2part[2048 + r] + f2part[4096 + r] + f2part[6144 + r];
      }
      __syncthreads();
      float lm = -1.0e30f;
      for (int i = t; i < 1024; i += 256) lm = fmaxf(lm, dSb[i]);
      lm = wmax(lm);
      if (lane == 0) redW[wv] = lm;
      __syncthreads();
      const float maxd = fmaxf(fmaxf(redW[0], redW[1]), fmaxf(redW[2], redW[3]));
      {
        const int r = wv, row = row0B + r;
        const float s = sSb[r];
        float m = s + maxd; m = m > 0.f ? m : ALPHA * m;
        float num[6] = {0.f,0.f,0.f,0.f,0.f,0.f};
        float den = 0.f;
        for (int j = lane; j < 1024; j += 64){
          float e = s + dSb[j]; e = e > 0.f ? e : ALPHA * e;
          float w = __expf(fminf(e - m, 0.f));
          den += w;
          const float* fr = &featS[j * 6];
          #pragma unroll
          for (int f = 0; f < 6; ++f) num[f] += w * fr[f];
        }
        den = wsum(den);
        #pragma unroll
        for (int f = 0; f < 6; ++f) num[f] = wsum(num[f]);
        if (lane == 0){
          const float* Lx_t = Lx + (size_t)step * 6144;
          float* h_t = h_all + (size_t)step * 6144;
          #pragma unroll
          for (int f = 0; f < 6; ++f){
            float hv = Lx_t[row * 6 + f] + num[f] / den;
            h_t[row * 6 + f] = hv;
            htS[r][f] = hv;
          }
        }
      }
      __syncthreads();
      {
        const int k = lane, rw = row0B + wv;
        float hv[6];
        #pragma unroll
        for (int f = 0; f < 6; ++f) hv[f] = htS[wv][f];
        #pragma unroll
        for (int hh = 0; hh < 4; ++hh){
          float acc2 = 0.f;
          #pragma unroll
          for (int f = 0; f < 6; ++f) acc2 += hv[f] * WnS[(hh * 6 + f) * 64 + k];
          VtP[((size_t)hh * 64 + k) * 1024 + rw] = __float2bfloat16(acc2);  // transposed
          float ps = wsum(acc2 * anS[hh * 128 + k]);
          float pd = wsum(acc2 * anS[hh * 128 + 64 + k]);
          if (k == 0){
            fh[((size_t)hh * 2 + 0) * 1024 + rw] = ps;
            fh[((size_t)hh * 2 + 1) * 1024 + rw] = pd;
          }
        }
      }
    }
    if (step < 11) gg.sync();
  }
}

// Dense output attend (K=6) over per-head partials (summed on load).
// 16 rows/block (grid.x = 64 per instance), b = blockIdx.y.
template<int MODE>
__launch_bounds__(256)
__global__ void k_attO(const float* __restrict__ hW2part, const float* __restrict__ f2part,
                       const float* __restrict__ addsrc, float* __restrict__ outf,
                       void* __restrict__ outv, int outOff, const int* __restrict__ flag)
{
  const int b = blockIdx.y;
  const int row0 = blockIdx.x * 16;
  const int t = threadIdx.x;
  const int wv = t >> 6, lane = t & 63;
  __shared__ float featS[6144];    // [1024][6]
  __shared__ float dS[1024];
  __shared__ float sS[16];
  __shared__ float redW[4];

  const float* hp = hW2part + (size_t)b * 24576;
  for (int i = t; i < 6144; i += 256)
    featS[i] = hp[i] + hp[6144 + i] + hp[12288 + i] + hp[18432 + i];
  const float* fp = f2part + (size_t)b * 8192;
  for (int i = t; i < 1024; i += 256)
    dS[i] = fp[1024 + i] + fp[3072 + i] + fp[5120 + i] + fp[7168 + i];
  if (t < 16){
    const int r = row0 + t;
    sS[t] = fp[r] + fp[2048 + r] + fp[4096 + r] + fp[6144 + r];
  }
  __syncthreads();
  float lm = -1.0e30f;
  for (int i = t; i < 1024; i += 256) lm = fmaxf(lm, dS[i]);
  lm = wmax(lm);
  if (lane == 0) redW[wv] = lm;
  __syncthreads();
  const float maxd = fmaxf(fmaxf(redW[0], redW[1]), fmaxf(redW[2], redW[3]));

  const int r = t >> 4, jq = t & 15;
  const int row = row0 + r;
  const float s = sS[r];
  float m = s + maxd; m = m > 0.f ? m : ALPHA * m;
  float num[6] = {0.f,0.f,0.f,0.f,0.f,0.f};
  float den = 0.f;
  for (int j = jq; j < 1024; j += 16){
    float e = s + dS[j]; e = e > 0.f ? e : ALPHA * e;
    float w = __expf(fminf(e - m, 0.f));
    den += w;
    const float* fr = &featS[j * 6];
    #pragma unroll
    for (int f = 0; f < 6; ++f) num[f] += w * fr[f];
  }
  #pragma unroll
  for (int mm = 1; mm < 16; mm <<= 1){
    den += __shfl_xor(den, mm, 64);
    #pragma unroll
    for (int f = 0; f < 6; ++f) num[f] += __shfl_xor(num[f], mm, 64);
  }

  if (jq == 0){
    if (MODE == 0){
      float* dst = outf + ((size_t)b * 1024 + row) * 6;
      #pragma unroll
      for (int f = 0; f < 6; ++f) dst[f] = num[f] / den;
    } else {
      const float* xsrc = addsrc + ((size_t)b * 1024 + row) * 6;
      const int base = outOff + b * 6144 + row * 6;
      if (*flag){
        float* dst = (float*)outv;
        #pragma unroll
        for (int f = 0; f < 6; ++f) dst[base + f] = xsrc[f] + num[f] / den;
      } else {
        __hip_bfloat16* dst = (__hip_bfloat16*)outv;
        #pragma unroll
        for (int f = 0; f < 6; ++f) dst[base + f] = __float2bfloat16(xsrc[f] + num[f] / den);
      }
    }
  }
}

extern "C" void kernel_launch(void* const* d_in, const int* in_sizes, int n_in,
                              void* d_out, int out_size, void* d_ws, size_t ws_size,
                              hipStream_t stream) {
  (void)in_sizes; (void)n_in; (void)out_size;

  // Adaptive chunking: fixed 232000 floats + CH*303104 per-chunk floats.
  const size_t avail = ws_size / 4;
  int CH = 0;
  const int cands[6] = {12, 6, 4, 3, 2, 1};
  for (int i = 0; i < 6; ++i){
    if (232000u + (size_t)cands[i] * 303104u <= avail){ CH = cands[i]; break; }
  }
  if (CH == 0) return;  // diagnostic: absmax 4.156 => ws smaller than proven bound

  float* ws = (float*)d_ws;
  size_t off = 0;
  int*   flag = (int*)(ws + off); off += 16;
  float* xs   = ws + off; off += 73728;
  float* wsW  = ws + off; off += 10800;
  float* Lx    = ws + off; off += 73728;
  float* h_all = ws + off; off += 73728;
  float* p2hW2 = ws + off; off += (size_t)CH * 24576;  // [b][4][1024][6] partials
  float* p2f2  = ws + off; off += (size_t)CH * 8192;   // [b][4][2][1024] partials
  float* hWc   = ws + off; off += (size_t)CH * 262144; // bf16 Vt (1,3) / bf16 VtP (2)
  float* fc    = ws + off; off += (size_t)CH * 8192;

  hipMemsetAsync(flag, 0, 4, stream);
  k_detect<<<288, 256, 0, stream>>>((const unsigned short*)d_in[0], 73728, flag);
  Ptr13 ptrs;
  for (int i = 0; i < 13; ++i) ptrs.p[i] = d_in[i];
  k_cvtAll<<<331, 256, 0, stream>>>(ptrs, xs, wsW, flag);

  const int dstoff[12] = {0,1536,2048,3584,3600,5136,5648,7184,7200,8736,9248,10784};
  float *Wx = wsW + dstoff[0], *ax = wsW + dstoff[1], *Wxo = wsW + dstoff[2], *axo = wsW + dstoff[3];
  float *Wh = wsW + dstoff[4], *ah = wsW + dstoff[5], *Who = wsW + dstoff[6], *aho = wsW + dstoff[7];
  float *Wy = wsW + dstoff[8], *ay = wsW + dstoff[9], *Wyo = wsW + dstoff[10], *ayo = wsW + dstoff[11];

  __hip_bfloat16* VtG = (__hip_bfloat16*)hWc;

  // Phase 1 (t-batched, MFMA attend): Lx[t] = pat_layer(x_t, Wx, ax, Wxo, axo)
  for (int t0 = 0; t0 < 12; t0 += CH){
    k_prepT<<<dim3(4, CH, 4), 256, 0, stream>>>(xs + (size_t)t0 * 6144, Wx, ax, VtG, fc);
    k_attM<<<dim3(64, CH), 256, 0, stream>>>(VtG, fc, Wxo, axo, p2hW2, p2f2);
    k_attO<0><<<dim3(64, CH), 256, 0, stream>>>(p2hW2, p2f2, nullptr, Lx + (size_t)t0 * 6144,
                                                nullptr, 0, flag);
  }

  // Phase 2: ONE cooperative kernel for all 12 recurrence steps.
  __hip_bfloat16* VtP = (__hip_bfloat16*)hWc;   // [4][64][1024] bf16 (transposed hWh)
  float* fh = fc;
  {
    void* kargs[] = { (void*)&Lx, (void*)&h_all, (void*)&Who, (void*)&aho,
                      (void*)&Wh, (void*)&ah, (void*)&VtP, (void*)&fh,
                      (void*)&p2hW2, (void*)&p2f2 };
    hipLaunchCooperativeKernel((const void*)k_phase2, dim3(256), dim3(256),
                               kargs, 0, stream);
  }

  // Phase 3 (t-batched, MFMA attend): y_t = x_t + pat_layer(h_t, Wy, ay, Wyo, ayo)
  for (int t0 = 0; t0 < 12; t0 += CH){
    k_prepT<<<dim3(4, CH, 4), 256, 0, stream>>>(h_all + (size_t)t0 * 6144, Wy, ay, VtG, fc);
    k_attM<<<dim3(64, CH), 256, 0, stream>>>(VtG, fc, Wyo, ayo, p2hW2, p2f2);
    k_attO<2><<<dim3(64, CH), 256, 0, stream>>>(p2hW2, p2f2, xs + (size_t)t0 * 6144, nullptr,
                                                d_out, t0 * 6144, flag);
  }
}

// Round 4
// 428.550 us; speedup vs baseline: 2.6005x; 2.6005x over previous
//
#include <hip/hip_runtime.h>
#include <hip/hip_bf16.h>

#define ALPHA 0.2f
// N=1024 particles, F_IN=6, NH=64, H=4 heads, T=12 steps.

typedef short bf16x8 __attribute__((ext_vector_type(8)));   // 8 bf16 (4 VGPRs)
typedef float f32x4 __attribute__((ext_vector_type(4)));

__device__ __forceinline__ float wsum(float v){
  #pragma unroll
  for (int m = 1; m < 64; m <<= 1) v += __shfl_xor(v, m, 64);
  return v;
}
__device__ __forceinline__ float wmax(float v){
  #pragma unroll
  for (int m = 1; m < 64; m <<= 1) v = fmaxf(v, __shfl_xor(v, m, 64));
  return v;
}

// Dtype detector: bf16 data never contains inf/NaN bit patterns (inputs finite);
// f32 data viewed as ushorts has ~0.78% such patterns. flag=1 -> f32; 0 -> bf16.
__global__ void k_detect(const unsigned short* __restrict__ s, int n, int* __restrict__ flag){
  int i = blockIdx.x * 256 + threadIdx.x;
  if (i < n){
    unsigned short u = s[i];
    if ((u & 0x7F80u) == 0x7F80u) atomicOr(flag, 1);
  }
}

// Merged conversion: states (73728 -> xs) + all 12 weight arrays (-> padded wsW).
struct Ptr13 { const void* p[13]; };
__global__ void k_cvtAll(Ptr13 src, float* __restrict__ xs, float* __restrict__ wsW,
                         const int* __restrict__ flag){
  const int n = blockIdx.x * 256 + threadIdx.x;
  const int F = *flag;
  if (n < 73728){
    xs[n] = F ? ((const float*)src.p[0])[n]
              : __bfloat162float(((const __hip_bfloat16*)src.p[0])[n]);
    return;
  }
  const int m = n - 73728;
  if (m >= 10788) return;
  const int segend[12] = {1536,2048,3584,3596,5132,5644,7180,7192,8728,9240,10776,10788};
  const int dstoff[12] = {0,1536,2048,3584,3600,5136,5648,7184,7200,8736,9248,10784};
  int seg = 0;
  #pragma unroll
  for (int i = 0; i < 12; ++i) if (m >= segend[i]) seg = i + 1;
  const int local = m - (seg ? segend[seg - 1] : 0);
  float v;
  if (F) v = ((const float*)src.p[seg + 1])[local];
  else   v = __bfloat162float(((const __hip_bfloat16*)src.p[seg + 1])[local]);
  wsW[dstoff[seg] + local] = v;
}

// Precompute Wa[layer][h][sd][6] = W_heads @ a_heads halves (scores are linear:
// f_src(row) = x . (W @ a_src)), plus zero-init the recurrent state VtP/fh.
// Replaces 2 memset dispatches and kills all score wsum-trees downstream.
__global__ void k_prew(const float* __restrict__ wsW, float* __restrict__ WaG,
                       float* __restrict__ VtPf, float* __restrict__ fh)
{
  const int gid = blockIdx.x * 256 + threadIdx.x;       // grid 96 blocks
  for (int i = gid; i < 131072; i += 24576) VtPf[i] = 0.f;
  if (gid < 8192) fh[gid] = 0.f;
  if (blockIdx.x == 0 && threadIdx.x < 144){
    const int d = threadIdx.x;
    const int L = d / 48, r2 = d % 48, h = r2 / 12, sd = (r2 % 12) / 6, f = r2 % 6;
    const int Woff[3] = {0, 3600, 7200};     // Wx, Wh, Wy
    const int aoff[3] = {1536, 5136, 8736};  // ax, ah, ay
    float s = 0.f;
    for (int k = 0; k < 64; ++k)
      s += wsW[Woff[L] + h * 384 + f * 64 + k] * wsW[aoff[L] + h * 128 + sd * 64 + k];
    WaG[((L * 4 + h) * 2 + sd) * 8 + f] = s;
  }
}

// Batched prep for MFMA attend (phase 1 only, layer 0): hW row in fp32, emitted
// bf16 V-TRANSPOSED Vt[(b*4+h)*64 + k][j] (row stride 1032) via LDS transpose.
// Scores via precomputed Wa (6-FMA dot). Block: 1 head (z), 256 rows (x), inst (y).
__launch_bounds__(256)
__global__ void k_prepT(const float* __restrict__ X, const float* __restrict__ W,
                        const float* __restrict__ WaG,
                        __hip_bfloat16* __restrict__ Vt, float* __restrict__ fsd)
{
  __shared__ float WS[384];    // W[h]: [6][64]
  __shared__ __align__(16) __hip_bfloat16 tileT[64 * 264];  // [k][row], pad 8
  const int t = threadIdx.x;
  const int b = blockIdx.y;
  const int h = blockIdx.z;
  const int row0 = blockIdx.x * 256;
  const int row = row0 + t;
  for (int i = t; i < 384; i += 256) WS[i] = W[h * 384 + i];
  __syncthreads();
  float x[6];
  const float* xp = X + ((size_t)b * 1024 + row) * 6;
  #pragma unroll
  for (int f = 0; f < 6; ++f) x[f] = xp[f];
  for (int k = 0; k < 64; ++k){
    float v = 0.f;
    #pragma unroll
    for (int f = 0; f < 6; ++f) v += x[f] * WS[f * 64 + k];
    tileT[k * 264 + t] = __float2bfloat16(v);
  }
  const float* was = WaG + h * 16;       // layer 0
  float fs = 0.f, fd = 0.f;
  #pragma unroll
  for (int f = 0; f < 6; ++f){ fs += x[f] * was[f]; fd += x[f] * was[8 + f]; }
  fsd[(((size_t)b * 4 + h) * 2 + 0) * 1024 + row] = fs;
  fsd[(((size_t)b * 4 + h) * 2 + 1) * 1024 + row] = fd;
  __syncthreads();
  const int k = t >> 2, seg = t & 3;
  __hip_bfloat16* dst = Vt + (((size_t)b * 4 + h) * 64 + k) * 1032 + row0 + seg * 64;
  const __hip_bfloat16* src = tileT + k * 264 + seg * 64;
  #pragma unroll
  for (int i = 0; i < 8; ++i)
    ((uint4*)dst)[i] = ((const uint4*)src)[i];
}

// MFMA head-attend: block = 1 head x 64 rows (4 waves x 16 rows), 64 feats.
// Softmax weights (A-fragments) fully in-register (row=lane&15, k=(lane>>4)*8+i).
// B-fragments read DIRECTLY from global Vt (L2-resident): no in-loop barriers.
__launch_bounds__(256)
__global__ void k_attM(const __hip_bfloat16* __restrict__ Vt, const float* __restrict__ fsd,
                       const float* __restrict__ Wout, const float* __restrict__ aout,
                       float* __restrict__ hW2part, float* __restrict__ f2part)
{
  const int h = blockIdx.x & 3;
  const int row0 = (blockIdx.x >> 2) * 64;
  const int b = blockIdx.y;
  const int t = threadIdx.x;
  const int wv = t >> 6, lane = t & 63;
  const int n = lane & 15, q = lane >> 4;
  const size_t bh = (size_t)b * 4 + h;

  __shared__ float dS[1024];
  __shared__ float WoS[384];
  __shared__ float aoS[12];
  __shared__ float redW[4];

  const float* fb = fsd + bh * 2048;
  float4 dv = *(const float4*)(fb + 1024 + t * 4);
  for (int i = t; i < 384; i += 256) WoS[i] = Wout[h * 384 + i];
  if (t < 12) aoS[t] = aout[t];
  *(float4*)&dS[t * 4] = dv;
  const float sW = fb[row0 + wv * 16 + n];        // this lane's attention-row score
  float lm = fmaxf(fmaxf(dv.x, dv.y), fmaxf(dv.z, dv.w));
  lm = wmax(lm);
  if (lane == 0) redW[wv] = lm;
  __syncthreads();
  const float maxd = fmaxf(fmaxf(redW[0], redW[1]), fmaxf(redW[2], redW[3]));
  float mW = sW + maxd; mW = fmaxf(mW, ALPHA * mW);   // leaky(sW+maxd) = row max of e

  const __hip_bfloat16* vbase = Vt + (bh * 64 + n) * 1032 + q * 8;
  f32x4 acc[4];
  #pragma unroll
  for (int nt = 0; nt < 4; ++nt) acc[nt] = (f32x4){0.f, 0.f, 0.f, 0.f};
  float den = 0.f;

  for (int jt = 0; jt < 16; ++jt){
    bf16x8 b0[4], b1[4];
    #pragma unroll
    for (int nt = 0; nt < 4; ++nt){
      b0[nt] = *(const bf16x8*)(vbase + nt * 16512 + jt * 64);
      b1[nt] = *(const bf16x8*)(vbase + nt * 16512 + jt * 64 + 32);
    }
    // A-fragments for this lane: rows n, j = jt*64 + {0,32} + q*8 + i
    const float* dp = &dS[jt * 64 + q * 8];
    float d0[8], d1[8];
    *(float4*)&d0[0] = *(const float4*)(dp);
    *(float4*)&d0[4] = *(const float4*)(dp + 4);
    *(float4*)&d1[0] = *(const float4*)(dp + 32);
    *(float4*)&d1[4] = *(const float4*)(dp + 36);
    bf16x8 a0, a1;
    #pragma unroll
    for (int i = 0; i < 8; ++i){
      float e0 = sW + d0[i]; e0 = fmaxf(e0, ALPHA * e0);
      __hip_bfloat16 w0 = __float2bfloat16(__expf(fminf(e0 - mW, 0.f)));
      a0[i] = __builtin_bit_cast(short, w0);
      den += __bfloat162float(w0);                  // den consistent with bf16 A
      float e1 = sW + d1[i]; e1 = fmaxf(e1, ALPHA * e1);
      __hip_bfloat16 w1 = __float2bfloat16(__expf(fminf(e1 - mW, 0.f)));
      a1[i] = __builtin_bit_cast(short, w1);
      den += __bfloat162float(w1);
    }
    #pragma unroll
    for (int nt = 0; nt < 4; ++nt)
      acc[nt] = __builtin_amdgcn_mfma_f32_16x16x32_bf16(a0, b0[nt], acc[nt], 0, 0, 0);
    #pragma unroll
    for (int nt = 0; nt < 4; ++nt)
      acc[nt] = __builtin_amdgcn_mfma_f32_16x16x32_bf16(a1, b1[nt], acc[nt], 0, 0, 0);
  }
  // full den per row n: reduce over the 4 q-lanes sharing row n
  den += __shfl_xor(den, 16, 64);
  den += __shfl_xor(den, 32, 64);

  // epilogue: D[row=q*4+reg][feat=nt*16+n]; /den, ELU, project to 6 feats.
  float o[4][6];
  #pragma unroll
  for (int reg = 0; reg < 4; ++reg)
    #pragma unroll
    for (int f = 0; f < 6; ++f) o[reg][f] = 0.f;
  #pragma unroll
  for (int reg = 0; reg < 4; ++reg){
    const float dn = __shfl(den, q * 4 + reg, 64);  // den of row q*4+reg (>= 1)
    #pragma unroll
    for (int nt = 0; nt < 4; ++nt){
      float v = acc[nt][reg] / dn;
      v = v > 0.f ? v : (__expf(v) - 1.f);          // ELU
      #pragma unroll
      for (int f = 0; f < 6; ++f) o[reg][f] += v * WoS[(nt * 16 + n) * 6 + f];
    }
  }
  #pragma unroll
  for (int mm = 1; mm < 16; mm <<= 1)
    #pragma unroll
    for (int reg = 0; reg < 4; ++reg)
      #pragma unroll
      for (int f = 0; f < 6; ++f) o[reg][f] += __shfl_xor(o[reg][f], mm, 64);
  if (n == 0){
    #pragma unroll
    for (int reg = 0; reg < 4; ++reg){
      const int row = row0 + wv * 16 + q * 4 + reg;
      float* hp = hW2part + bh * 6144 + row * 6;
      float fs = 0.f, fd = 0.f;
      #pragma unroll
      for (int f = 0; f < 6; ++f){
        hp[f] = o[reg][f];
        fs += o[reg][f] * aoS[f]; fd += o[reg][f] * aoS[6 + f];
      }
      f2part[bh * 2048 + row]        = fs;
      f2part[bh * 2048 + 1024 + row] = fd;
    }
  }
}

// Phase-2 MFMA head-attend: grid 256 blocks; block = 1 head x 16 rows; 4 waves
// SPLIT the j-dimension (4 jt-tiles each), in-register softmax weights,
// B-frags direct from L2 (VtP [h][feat][row] bf16, written by k_attB).
__launch_bounds__(256)
__global__ void k_attP(const __hip_bfloat16* __restrict__ VtP, const float* __restrict__ fsd,
                       const float* __restrict__ Wout, const float* __restrict__ aout,
                       float* __restrict__ hW2part, float* __restrict__ f2part)
{
  const int h = blockIdx.x & 3;
  const int row0 = (blockIdx.x >> 2) * 16;
  const int t = threadIdx.x;
  const int wv = t >> 6, lane = t & 63;
  const int n = lane & 15, q = lane >> 4;

  __shared__ float dS[1024];
  __shared__ float WoS[384];
  __shared__ float aoS[12];
  __shared__ float redW[4];
  __shared__ float accS[4][16][65];   // [wave][row][feat], +1 pad
  __shared__ float denP[4][16];

  const float* fb = fsd + (size_t)h * 2048;
  float4 dv = *(const float4*)(fb + 1024 + t * 4);
  for (int i = t; i < 384; i += 256) WoS[i] = Wout[h * 384 + i];
  if (t < 12) aoS[t] = aout[t];
  *(float4*)&dS[t * 4] = dv;
  const float sW = fb[row0 + n];
  float lm = fmaxf(fmaxf(dv.x, dv.y), fmaxf(dv.z, dv.w));
  lm = wmax(lm);
  if (lane == 0) redW[wv] = lm;
  __syncthreads();
  const float maxd = fmaxf(fmaxf(redW[0], redW[1]), fmaxf(redW[2], redW[3]));
  float mW = sW + maxd; mW = fmaxf(mW, ALPHA * mW);

  const __hip_bfloat16* vbase = VtP + ((size_t)h * 64 + n) * 1024 + q * 8;
  f32x4 acc[4];
  #pragma unroll
  for (int nt = 0; nt < 4; ++nt) acc[nt] = (f32x4){0.f, 0.f, 0.f, 0.f};
  float den = 0.f;

  #pragma unroll
  for (int u = 0; u < 4; ++u){
    const int jt = wv * 4 + u;
    bf16x8 b0[4], b1[4];
    #pragma unroll
    for (int nt = 0; nt < 4; ++nt){
      b0[nt] = *(const bf16x8*)(vbase + nt * 16384 + jt * 64);
      b1[nt] = *(const bf16x8*)(vbase + nt * 16384 + jt * 64 + 32);
    }
    const float* dp = &dS[jt * 64 + q * 8];
    float d0[8], d1[8];
    *(float4*)&d0[0] = *(const float4*)(dp);
    *(float4*)&d0[4] = *(const float4*)(dp + 4);
    *(float4*)&d1[0] = *(const float4*)(dp + 32);
    *(float4*)&d1[4] = *(const float4*)(dp + 36);
    bf16x8 a0, a1;
    #pragma unroll
    for (int i = 0; i < 8; ++i){
      float e0 = sW + d0[i]; e0 = fmaxf(e0, ALPHA * e0);
      __hip_bfloat16 w0 = __float2bfloat16(__expf(fminf(e0 - mW, 0.f)));
      a0[i] = __builtin_bit_cast(short, w0);
      den += __bfloat162float(w0);
      float e1 = sW + d1[i]; e1 = fmaxf(e1, ALPHA * e1);
      __hip_bfloat16 w1 = __float2bfloat16(__expf(fminf(e1 - mW, 0.f)));
      a1[i] = __builtin_bit_cast(short, w1);
      den += __bfloat162float(w1);
    }
    #pragma unroll
    for (int nt = 0; nt < 4; ++nt)
      acc[nt] = __builtin_amdgcn_mfma_f32_16x16x32_bf16(a0, b0[nt], acc[nt], 0, 0, 0);
    #pragma unroll
    for (int nt = 0; nt < 4; ++nt)
      acc[nt] = __builtin_amdgcn_mfma_f32_16x16x32_bf16(a1, b1[nt], acc[nt], 0, 0, 0);
  }
  den += __shfl_xor(den, 16, 64);
  den += __shfl_xor(den, 32, 64);
  if (lane < 16) denP[wv][lane] = den;
  #pragma unroll
  for (int nt = 0; nt < 4; ++nt)
    #pragma unroll
    for (int reg = 0; reg < 4; ++reg)
      accS[wv][q * 4 + reg][nt * 16 + n] = acc[nt][reg];
  __syncthreads();

  const int r = t >> 4, kq = t & 15;
  const float dn = denP[0][r] + denP[1][r] + denP[2][r] + denP[3][r];   // >= 1
  float o[6] = {0.f,0.f,0.f,0.f,0.f,0.f};
  #pragma unroll
  for (int j4 = 0; j4 < 4; ++j4){
    const int k = kq * 4 + j4;
    float v = (accS[0][r][k] + accS[1][r][k] + accS[2][r][k] + accS[3][r][k]) / dn;
    v = v > 0.f ? v : (__expf(v) - 1.f);          // ELU
    #pragma unroll
    for (int f = 0; f < 6; ++f) o[f] += v * WoS[k * 6 + f];
  }
  #pragma unroll
  for (int mm = 1; mm < 16; mm <<= 1)
    #pragma unroll
    for (int f = 0; f < 6; ++f) o[f] += __shfl_xor(o[f], mm, 64);
  if (kq == 0){
    const int row = row0 + r;
    float* hp = hW2part + (size_t)h * 6144 + row * 6;
    float fs = 0.f, fd = 0.f;
    #pragma unroll
    for (int f = 0; f < 6; ++f){
      hp[f] = o[f];
      fs += o[f] * aoS[f]; fd += o[f] * aoS[6 + f];
    }
    f2part[(size_t)h * 2048 + row]        = fs;
    f2part[(size_t)h * 2048 + 1024 + row] = fd;
  }
}

// Phase-2 stage B: sum per-head partials, output attend (K=6), h_t = Lx + out.
// Then (fused): next-step recurrence prep (VtP bf16 transposed + fh scores via
// precomputed Wa) AND phase-3 prep (VtY bf16 transposed + fsdY scores) — this
// replaces the phase-3 k_prepT dispatch and all score wsum-trees.
__launch_bounds__(256)
__global__ void k_attB(const float* __restrict__ hW2part, const float* __restrict__ f2part,
                       const float* __restrict__ Lx_t,
                       const float* __restrict__ Wh, const float* __restrict__ Wy,
                       const float* __restrict__ WaG,
                       __hip_bfloat16* __restrict__ VtP, float* __restrict__ fh,
                       __hip_bfloat16* __restrict__ VtY_t, float* __restrict__ fsdY_t)
{
  const int t = threadIdx.x;
  const int row0 = blockIdx.x * 4;
  const int wv = t >> 6, lane = t & 63;
  __shared__ __align__(16) float featS[6144];
  __shared__ __align__(16) float dSb[1024];
  __shared__ float sSb[4];
  __shared__ float redW[4];
  __shared__ float htS[4][6];
  __shared__ float WnS[1536];
  __shared__ float WyS[1536];

  {
    const float4* h4 = (const float4*)hW2part;
    for (int i = t; i < 1536; i += 256){
      float4 a = h4[i], b = h4[1536 + i], c = h4[3072 + i], d = h4[4608 + i];
      float4 r; r.x = a.x+b.x+c.x+d.x; r.y = a.y+b.y+c.y+d.y;
      r.z = a.z+b.z+c.z+d.z; r.w = a.w+b.w+c.w+d.w;
      *(float4*)&featS[i * 4] = r;
    }
    const float4* f4 = (const float4*)f2part;
    {
      const int i = t;
      if (i < 256){
        float4 a = f4[256 + i], b = f4[768 + i], c = f4[1280 + i], d = f4[1792 + i];
        float4 r; r.x = a.x+b.x+c.x+d.x; r.y = a.y+b.y+c.y+d.y;
        r.z = a.z+b.z+c.z+d.z; r.w = a.w+b.w+c.w+d.w;
        *(float4*)&dSb[i * 4] = r;
      }
    }
  }
  if (t < 4){
    const int r = row0 + t;
    sSb[t] = f2part[r] + f2part[2048 + r] + f2part[4096 + r] + f2part[6144 + r];
  }
  for (int i = t; i < 1536; i += 256){ WnS[i] = Wh[i]; WyS[i] = Wy[i]; }
  __syncthreads();
  float lm = -1.0e30f;
  for (int i = t; i < 1024; i += 256) lm = fmaxf(lm, dSb[i]);
  lm = wmax(lm);
  if (lane == 0) redW[wv] = lm;
  __syncthreads();
  const float maxd = fmaxf(fmaxf(redW[0], redW[1]), fmaxf(redW[2], redW[3]));
  {
    const int r = wv, row = row0 + r;
    const float s = sSb[r];
    float m = s + maxd; m = m > 0.f ? m : ALPHA * m;
    float num[6] = {0.f,0.f,0.f,0.f,0.f,0.f};
    float den = 0.f;
    for (int j = lane; j < 1024; j += 64){
      float e = s + dSb[j]; e = e > 0.f ? e : ALPHA * e;
      float w = __expf(fminf(e - m, 0.f));
      den += w;
      const float* fr = &featS[j * 6];
      #pragma unroll
      for (int f = 0; f < 6; ++f) num[f] += w * fr[f];
    }
    den = wsum(den);
    #pragma unroll
    for (int f = 0; f < 6; ++f) num[f] = wsum(num[f]);
    if (lane == 0){
      #pragma unroll
      for (int f = 0; f < 6; ++f)
        htS[r][f] = Lx_t[row * 6 + f] + num[f] / den;
    }
  }
  __syncthreads();
  // next-step prep: thread (wv=row, lane=k) emits hW for recurrence (Wh -> VtP)
  // and for the y-layer (Wy -> VtY), both bf16 transposed [h][k][row].
  {
    const int k = lane, rw = row0 + wv;
    float hv[6];
    #pragma unroll
    for (int f = 0; f < 6; ++f) hv[f] = htS[wv][f];
    #pragma unroll
    for (int hh = 0; hh < 4; ++hh){
      float a2 = 0.f, a3 = 0.f;
      #pragma unroll
      for (int f = 0; f < 6; ++f){
        a2 += hv[f] * WnS[(hh * 6 + f) * 64 + k];
        a3 += hv[f] * WyS[(hh * 6 + f) * 64 + k];
      }
      VtP[((size_t)hh * 64 + k) * 1024 + rw]   = __float2bfloat16(a2);
      VtY_t[((size_t)hh * 64 + k) * 1032 + rw] = __float2bfloat16(a3);
    }
  }
  // scores via precomputed Wa: 16 scores/row (2 layers x 4 heads x src/dst)
  if (t < 64){
    const int r = t >> 4, u = t & 15;
    const int L = 1 + (u >> 3), hh = (u >> 1) & 3, sd = u & 1;
    const float* wa = WaG + ((L * 4 + hh) * 2 + sd) * 8;
    float s = 0.f;
    #pragma unroll
    for (int f = 0; f < 6; ++f) s += htS[r][f] * wa[f];
    float* dst = (L == 1) ? fh : fsdY_t;
    dst[hh * 2048 + sd * 1024 + row0 + r] = s;
  }
}

// Dense output attend (K=6) over per-head partials (summed on load).
// 16 rows/block (grid.x = 64 per instance), b = blockIdx.y.
template<int MODE>
__launch_bounds__(256)
__global__ void k_attO(const float* __restrict__ hW2part, const float* __restrict__ f2part,
                       const float* __restrict__ addsrc, float* __restrict__ outf,
                       void* __restrict__ outv, int outOff, const int* __restrict__ flag)
{
  const int b = blockIdx.y;
  const int row0 = blockIdx.x * 16;
  const int t = threadIdx.x;
  const int wv = t >> 6, lane = t & 63;
  __shared__ __align__(16) float featS[6144];    // [1024][6]
  __shared__ __align__(16) float dS[1024];
  __shared__ float sS[16];
  __shared__ float redW[4];

  {
    const float4* h4 = (const float4*)(hW2part + (size_t)b * 24576);
    for (int i = t; i < 1536; i += 256){
      float4 a = h4[i], bb = h4[1536 + i], c = h4[3072 + i], d = h4[4608 + i];
      float4 r; r.x = a.x+bb.x+c.x+d.x; r.y = a.y+bb.y+c.y+d.y;
      r.z = a.z+bb.z+c.z+d.z; r.w = a.w+bb.w+c.w+d.w;
      *(float4*)&featS[i * 4] = r;
    }
    const float4* f4 = (const float4*)(f2part + (size_t)b * 8192);
    if (t < 256){
      float4 a = f4[256 + t], bb = f4[768 + t], c = f4[1280 + t], d = f4[1792 + t];
      float4 r; r.x = a.x+bb.x+c.x+d.x; r.y = a.y+bb.y+c.y+d.y;
      r.z = a.z+bb.z+c.z+d.z; r.w = a.w+bb.w+c.w+d.w;
      *(float4*)&dS[t * 4] = r;
    }
  }
  const float* fp = f2part + (size_t)b * 8192;
  if (t < 16){
    const int r = row0 + t;
    sS[t] = fp[r] + fp[2048 + r] + fp[4096 + r] + fp[6144 + r];
  }
  __syncthreads();
  float lm = -1.0e30f;
  for (int i = t; i < 1024; i += 256) lm = fmaxf(lm, dS[i]);
  lm = wmax(lm);
  if (lane == 0) redW[wv] = lm;
  __syncthreads();
  const float maxd = fmaxf(fmaxf(redW[0], redW[1]), fmaxf(redW[2], redW[3]));

  const int r = t >> 4, jq = t & 15;
  const int row = row0 + r;
  const float s = sS[r];
  float m = s + maxd; m = m > 0.f ? m : ALPHA * m;
  float num[6] = {0.f,0.f,0.f,0.f,0.f,0.f};
  float den = 0.f;
  for (int j = jq; j < 1024; j += 16){
    float e = s + dS[j]; e = e > 0.f ? e : ALPHA * e;
    float w = __expf(fminf(e - m, 0.f));
    den += w;
    const float* fr = &featS[j * 6];
    #pragma unroll
    for (int f = 0; f < 6; ++f) num[f] += w * fr[f];
  }
  #pragma unroll
  for (int mm = 1; mm < 16; mm <<= 1){
    den += __shfl_xor(den, mm, 64);
    #pragma unroll
    for (int f = 0; f < 6; ++f) num[f] += __shfl_xor(num[f], mm, 64);
  }

  if (jq == 0){
    if (MODE == 0){
      float* dst = outf + ((size_t)b * 1024 + row) * 6;
      #pragma unroll
      for (int f = 0; f < 6; ++f) dst[f] = num[f] / den;
    } else {
      const float* xsrc = addsrc + ((size_t)b * 1024 + row) * 6;
      const int base = outOff + b * 6144 + row * 6;
      if (*flag){
        float* dst = (float*)outv;
        #pragma unroll
        for (int f = 0; f < 6; ++f) dst[base + f] = xsrc[f] + num[f] / den;
      } else {
        __hip_bfloat16* dst = (__hip_bfloat16*)outv;
        #pragma unroll
        for (int f = 0; f < 6; ++f) dst[base + f] = __float2bfloat16(xsrc[f] + num[f] / den);
      }
    }
  }
}

extern "C" void kernel_launch(void* const* d_in, const int* in_sizes, int n_in,
                              void* d_out, int out_size, void* d_ws, size_t ws_size,
                              hipStream_t stream) {
  (void)in_sizes; (void)n_in; (void)out_size;

  // Adaptive chunking: fixed 1981248 floats + CH*303104 per-chunk floats.
  const size_t avail = ws_size / 4;
  int CH = 0;
  const int cands[6] = {12, 6, 4, 3, 2, 1};
  for (int i = 0; i < 6; ++i){
    if (1981248u + (size_t)cands[i] * 303104u <= avail){ CH = cands[i]; break; }
  }
  if (CH == 0) return;  // diagnostic: ws smaller than proven bound

  float* ws = (float*)d_ws;
  size_t off = 0;
  int*   flag = (int*)(ws + off); off += 16;
  float* xs   = ws + off; off += 73728;
  float* wsW  = ws + off; off += 10800;
  float* Lx   = ws + off; off += 73728;
  float* WaG  = ws + off; off += 256;
  float* VtPf = ws + off; off += 131072;            // [4][64][1024] bf16
  float* fh   = ws + off; off += 8192;
  float* VtYf = ws + off; off += 1585152;           // [12][4][64][1032] bf16
  float* fsdY = ws + off; off += 98304;             // [12][4][2][1024] f32
  float* p2hW2 = ws + off; off += (size_t)CH * 24576;
  float* p2f2  = ws + off; off += (size_t)CH * 8192;
  float* VtGf  = ws + off; off += (size_t)CH * 262144;  // phase-1 bf16 Vt
  float* fc    = ws + off; off += (size_t)CH * 8192;

  hipMemsetAsync(flag, 0, 4, stream);
  k_detect<<<288, 256, 0, stream>>>((const unsigned short*)d_in[0], 73728, flag);
  Ptr13 ptrs;
  for (int i = 0; i < 13; ++i) ptrs.p[i] = d_in[i];
  k_cvtAll<<<331, 256, 0, stream>>>(ptrs, xs, wsW, flag);
  k_prew<<<96, 256, 0, stream>>>(wsW, WaG, VtPf, fh);

  const int dstoff[12] = {0,1536,2048,3584,3600,5136,5648,7184,7200,8736,9248,10784};
  float *Wx = wsW + dstoff[0], *Wxo = wsW + dstoff[2], *axo = wsW + dstoff[3];
  float *Wh = wsW + dstoff[4], *Who = wsW + dstoff[6], *aho = wsW + dstoff[7];
  float *Wy = wsW + dstoff[8], *Wyo = wsW + dstoff[10], *ayo = wsW + dstoff[11];

  __hip_bfloat16* VtG = (__hip_bfloat16*)VtGf;
  __hip_bfloat16* VtP = (__hip_bfloat16*)VtPf;
  __hip_bfloat16* VtY = (__hip_bfloat16*)VtYf;

  // Phase 1 (t-batched, MFMA attend): Lx[t] = pat_layer(x_t, Wx, ax, Wxo, axo)
  for (int t0 = 0; t0 < 12; t0 += CH){
    k_prepT<<<dim3(4, CH, 4), 256, 0, stream>>>(xs + (size_t)t0 * 6144, Wx, WaG, VtG, fc);
    k_attM<<<dim3(64, CH), 256, 0, stream>>>(VtG, fc, Wxo, axo, p2hW2, p2f2);
    k_attO<0><<<dim3(64, CH), 256, 0, stream>>>(p2hW2, p2f2, nullptr, Lx + (size_t)t0 * 6144,
                                                nullptr, 0, flag);
  }

  // Phase 2 (sequential): MFMA attend (P) + combine/advance (B) per step.
  // k_attB also emits phase-3's VtY/fsdY (kills the phase-3 prepT dispatch).
  for (int t = 0; t < 12; ++t){
    k_attP<<<dim3(256, 1), 256, 0, stream>>>(VtP, fh, Who, aho, p2hW2, p2f2);
    k_attB<<<256, 256, 0, stream>>>(p2hW2, p2f2, Lx + (size_t)t * 6144,
                                    Wh, Wy, WaG, VtP, fh,
                                    VtY + (size_t)t * 264192, fsdY + (size_t)t * 8192);
  }

  // Phase 3 (t-batched, MFMA attend): y_t = x_t + pat_layer(h_t, Wy, ay, Wyo, ayo)
  for (int t0 = 0; t0 < 12; t0 += CH){
    k_attM<<<dim3(64, CH), 256, 0, stream>>>(VtY + (size_t)t0 * 264192, fsdY + (size_t)t0 * 8192,
                                             Wyo, ayo, p2hW2, p2f2);
    k_attO<2><<<dim3(64, CH), 256, 0, stream>>>(p2hW2, p2f2, xs + (size_t)t0 * 6144, nullptr,
                                                d_out, t0 * 6144, flag);
  }
}